// Round 5
// baseline (1570.278 us; speedup 1.0000x reference)
//
#include <hip/hip_runtime.h>
#include <hip/hip_fp16.h>
#include <stdint.h>

#define N_NODES 100000
#define N_EDGES 3200000
#define BN      128                   // nodes per dst-bucket
#define NB      782                   // ceil(N_NODES / BN)
// histogram granularity (fine)
#define NCH_H   1024
#define CH_H    (N_EDGES / NCH_H)     // 3125
#define CPL     (NCH_H / 64)          // 16 chunks per lane in chunkscan
#define PAD_PER 98                    // nodes padded per hist block
// scatter granularity: 512 chunks -> 2 resident blocks/CU
#define NCH_S   512
#define CH_S    (N_EDGES / NCH_S)     // 6250
#define FPS     (NCH_H / NCH_S)       // 2 fine chunks per scatter chunk
#define BS1     1024                  // scatter1 block size
#define S1_IT   ((CH_S + BS1 - 1) / BS1)  // 7
#define BS2     512                   // scatter2 block size
#define S2_CAP  4608                  // scatter2 LDS stage capacity (>= max bucket n)
#define R2IT    9                     // scatter2 reg-cache depth (9*512=4608 >= max bucket)
#define BLOCK   256
#define GN8     3125                  // node-groups of 32 nodes (256 thr, 8 lanes/node)
#define LGRID   1024                  // fused layers grid: 4 blocks/CU, all resident
#define W_SCALE 32767.0f
#define W_INV   (1.0f / 32767.0f)

// ---------------------------------------------------------------------------
// Stage 1: per-subchunk bucket histogram + fused x->fp16 padding
// ---------------------------------------------------------------------------
__global__ void hist_kernel(const int* __restrict__ dst, int* __restrict__ hist_g,
                            const float* __restrict__ x, __half* __restrict__ xpad) {
    __shared__ int h[NB];
    for (int b = threadIdx.x; b < NB; b += BLOCK) h[b] = 0;
    {
        int i = blockIdx.x * PAD_PER + threadIdx.x;
        if (threadIdx.x < PAD_PER && i < N_NODES) {
            const float* xr = x + (size_t)i * 6;
            __half2 hh[4];
            hh[0] = __halves2half2(__float2half(xr[0]), __float2half(xr[1]));
            hh[1] = __halves2half2(__float2half(xr[2]), __float2half(xr[3]));
            hh[2] = __halves2half2(__float2half(xr[4]), __float2half(xr[5]));
            hh[3] = __halves2half2(__float2half(0.f),   __float2half(0.f));
            *(uint4*)(xpad + (size_t)i * 8) = *(uint4*)hh;
        }
    }
    __syncthreads();
    const int c  = blockIdx.x;
    const int k0 = c * CH_H;
    for (int k = threadIdx.x; k < CH_H; k += BLOCK)
        atomicAdd(&h[dst[k0 + k] >> 7], 1);
    __syncthreads();
    for (int b = threadIdx.x; b < NB; b += BLOCK)
        hist_g[c * NB + b] = h[b];
}

// ---------------------------------------------------------------------------
// Stage 2a: per-bucket exclusive scan over the 1024 subchunk counts
// ---------------------------------------------------------------------------
__global__ void chunkscan_kernel(const int* __restrict__ hist_g,
                                 int* __restrict__ off_g, int* __restrict__ tot) {
    int w    = (blockIdx.x * blockDim.x + threadIdx.x) >> 6;
    int lane = threadIdx.x & 63;
    if (w >= NB) return;
    int v[CPL];
    int ls = 0;
    const int cbase = lane * CPL;
    #pragma unroll
    for (int i = 0; i < CPL; ++i) { v[i] = hist_g[(cbase + i) * NB + w]; ls += v[i]; }
    int run = ls;
    #pragma unroll
    for (int d = 1; d < 64; d <<= 1) {
        int u = __shfl_up(run, d);
        if (lane >= d) run += u;
    }
    int acc = run - ls;
    #pragma unroll
    for (int i = 0; i < CPL; ++i) { off_g[(cbase + i) * NB + w] = acc; acc += v[i]; }
    if (lane == 63) tot[w] = acc;
}

// ---------------------------------------------------------------------------
// Stage 2b: exclusive scan of NB bucket totals (one wg) + zero the sync
// slots used by the fused layers kernel (barriers [0..7], steal ctrs [8..15])
// ---------------------------------------------------------------------------
#define SCAN_T   1024
__global__ void scan_kernel(const int* __restrict__ cnt, int* __restrict__ bstart,
                            int* __restrict__ sync_ws) {
    __shared__ int part[SCAN_T];
    int t = threadIdx.x;
    if (t < 16) sync_ws[t] = 0;
    int v = (t < NB) ? cnt[t] : 0;
    part[t] = v;
    __syncthreads();
    for (int off = 1; off < SCAN_T; off <<= 1) {
        int u = (t >= off) ? part[t - off] : 0;
        __syncthreads();
        part[t] += u;
        __syncthreads();
    }
    if (t < NB) bstart[t] = part[t] - v;
}

// ---------------------------------------------------------------------------
// Stage 3: scatter pass 1 — full-record LDS stage, all-coalesced global IO.
// ---------------------------------------------------------------------------
__global__ void __launch_bounds__(BS1)
scatter1_kernel(const int* __restrict__ src, const int* __restrict__ dst,
                const float* __restrict__ w,
                const int* __restrict__ bstart, const int* __restrict__ off_g,
                const int* __restrict__ hist_g,
                uint2* __restrict__ rec1) {
    __shared__ uint2 stage[CH_S];      // 50000 B: full records
    __shared__ int h[NB];
    __shared__ int delta[NB];
    __shared__ int wtot[BS1 / 64];

    const int c  = blockIdx.x;
    const int k0 = c * CH_S;
    const int t  = threadIdx.x;

    // phase 0: issue all chunk loads (coalesced) before the scan phases
    int      dv[S1_IT];
    uint32_t sv[S1_IT];
    float    wv[S1_IT];
    #pragma unroll
    for (int i = 0; i < S1_IT; ++i) {
        int k = t + i * BS1;
        if (k < CH_S) {
            dv[i] = dst[k0 + k];
            sv[i] = (uint32_t)src[k0 + k];
            wv[i] = w[k0 + k];
        }
    }

    // phase 1: local bucket counts from hist_g (no dst pass, no atomics)
    for (int b = t; b < NB; b += BS1) {
        int s = 0;
        #pragma unroll
        for (int f = 0; f < FPS; ++f)
            s += hist_g[(size_t)(FPS * c + f) * NB + b];
        h[b] = s;
    }
    __syncthreads();

    // phase 2: block scan of h -> cursor start (in h) + delta
    {
        const int base = t * 2;          // 2048 >= NB
        int v[2], ls = 0;
        #pragma unroll
        for (int i = 0; i < 2; ++i) {
            int idx = base + i;
            v[i] = (idx < NB) ? h[idx] : 0;
            ls += v[i];
        }
        int lane = t & 63, wvi = t >> 6;
        int run = ls;
        #pragma unroll
        for (int d = 1; d < 64; d <<= 1) {
            int u = __shfl_up(run, d);
            if (lane >= d) run += u;
        }
        if (lane == 63) wtot[wvi] = run;
        __syncthreads();
        int wexcl = 0;
        for (int i = 0; i < wvi; ++i) wexcl += wtot[i];
        int excl = wexcl + run - ls;
        #pragma unroll
        for (int i = 0; i < 2; ++i) {
            int idx = base + i;
            if (idx < NB) {
                int gb = bstart[idx] + off_g[(size_t)(FPS * c) * NB + idx];
                h[idx]     = excl;
                delta[idx] = gb - excl;
                excl += v[i];
            }
        }
    }
    __syncthreads();

    // phase 3: full-record scatter into LDS stage (LDS cursors)
    #pragma unroll
    for (int i = 0; i < S1_IT; ++i) {
        int k = t + i * BS1;
        if (k < CH_S) {
            int d = dv[i];
            int b = d >> 7;
            int pos = atomicAdd(&h[b], 1);
            uint32_t w15 = (uint32_t)__float2uint_rn(wv[i] * W_SCALE);
            uint2 r;
            r.x = sv[i] | ((uint32_t)(d & 127) << 17);
            r.y = w15 | ((uint32_t)b << 15);
            stage[pos] = r;
        }
    }
    __syncthreads();

    // phase 4: sequential LDS read -> coalesced global store (runs of ~8)
    #pragma unroll
    for (int i = 0; i < S1_IT; ++i) {
        int k = t + i * BS1;
        if (k < CH_S) {
            uint2 r = stage[k];
            int b = (int)(r.y >> 15);
            rec1[delta[b] + k] = r;
        }
    }
}

// ---------------------------------------------------------------------------
// Stage 4: scatter pass 2 — node-sort each 128-node bucket through an LDS
// stage. rec1 register-cached across the two passes.
// Emits 4 B rec2 = src(17) | w15(15)<<17.
// ---------------------------------------------------------------------------
__global__ void __launch_bounds__(BS2)
scatter2_kernel(const uint2* __restrict__ rec1,
                const int* __restrict__ bstart, const int* __restrict__ tot,
                uint32_t* __restrict__ rec2,
                int* __restrict__ row_start, int* __restrict__ cnt) {
    __shared__ int h[BN];
    __shared__ int cur[BN];
    __shared__ int wtot2[2];
    __shared__ uint32_t stage[S2_CAP];
    const int b  = blockIdx.x;
    const int s0 = bstart[b];
    const int n  = tot[b];
    const int t  = threadIdx.x;
    if (t < BN) h[t] = 0;
    __syncthreads();

    uint2 rv[R2IT];
    #pragma unroll
    for (int i = 0; i < R2IT; ++i) {
        int k = t + i * BS2;
        uint2 r = (k < n) ? rec1[s0 + k] : make_uint2(0u, 0u);
        rv[i] = r;
        if (k < n) atomicAdd(&h[r.x >> 17], 1);
    }
    for (int k = t + R2IT * BS2; k < n; k += BS2)
        atomicAdd(&h[rec1[s0 + k].x >> 17], 1);
    __syncthreads();

    // two-wave exclusive scan over BN=128 counters
    int v = 0, run = 0;
    if (t < BN) {
        v = h[t];
        run = v;
        int lane = t & 63;
        #pragma unroll
        for (int d = 1; d < 64; d <<= 1) {
            int u = __shfl_up(run, d);
            if (lane >= d) run += u;
        }
        if (lane == 63) wtot2[t >> 6] = run;
    }
    __syncthreads();
    if (t < BN) {
        int excl = run - v + ((t >= 64) ? wtot2[0] : 0);
        cur[t] = excl;
        int node = b * BN + t;
        if (node < N_NODES) { row_start[node] = s0 + excl; cnt[node] = v; }
    }
    __syncthreads();

    #pragma unroll
    for (int i = 0; i < R2IT; ++i) {
        int k = t + i * BS2;
        if (k < n) {
            uint2 r = rv[i];
            int dl = (int)(r.x >> 17);
            uint32_t r2 = (r.x & 0x1FFFF) | ((r.y & 0x7FFF) << 17);
            int pos = atomicAdd(&cur[dl], 1);
            if (pos < S2_CAP) stage[pos] = r2;
            else              rec2[s0 + pos] = r2;
        }
    }
    for (int k = t + R2IT * BS2; k < n; k += BS2) {
        uint2 r = rec1[s0 + k];
        int dl = (int)(r.x >> 17);
        uint32_t r2 = (r.x & 0x1FFFF) | ((r.y & 0x7FFF) << 17);
        int pos = atomicAdd(&cur[dl], 1);
        if (pos < S2_CAP) stage[pos] = r2;
        else              rec2[s0 + pos] = r2;
    }
    __syncthreads();
    for (int i = t; i < n && i < S2_CAP; i += BS2)
        rec2[s0 + i] = stage[i];
}

// ---------------------------------------------------------------------------
// Fused layer pipeline: layer0 + 4 gather stages in ONE plain-launched
// kernel. Grid sync = manual device-scope barrier (cooperative API fails
// under graph capture — R4 post-mortem). Residency guarantee:
// __launch_bounds__(256,4) (<=128 VGPR, 3.5 KB LDS) -> 4 blocks/CU, grid
// 1024 = 4*256 CUs, all co-resident. Work distribution per stage is
// atomic work-stealing (3125 groups; static 4-vs-3 split costs ~30% tail).
// ---------------------------------------------------------------------------
struct LayerArgs {
    const __half* xpad;
    const uint32_t* rec;
    const int* row_start;
    const int* cnt;
    const float* wrel0; const float* brel0; const float* wroot0;
    const float* wrel1; const float* brel1; const float* wroot1;
    const float* wrel2; const float* brel2; const float* wroot2;
    const float* wrel3; const float* brel3; const float* wroot3;
    const float* wrel4; const float* brel4; const float* wroot4;
    __half* pA; __half* pB;
    float* oA; float* oB;
    float* out;
    int* sync_ws;   // [0..7] barrier slots, [8..15] steal counters
};

__device__ __forceinline__ void gsync(int* bar, int s) {
    __threadfence();                 // device-scope release (cross-XCD G16)
    __syncthreads();
    if (threadIdx.x == 0) {
        __hip_atomic_fetch_add(&bar[s], 1, __ATOMIC_ACQ_REL, __HIP_MEMORY_SCOPE_AGENT);
        while (__hip_atomic_load(&bar[s], __ATOMIC_ACQUIRE, __HIP_MEMORY_SCOPE_AGENT) < LGRID) {}
    }
    __syncthreads();
    __threadfence();                 // acquire side
}

__device__ __forceinline__ void layer0_body(
    int node, int q,
    const __half* __restrict__ xpad, const uint32_t* __restrict__ rec,
    const int* __restrict__ row_start, const int* __restrict__ cnt,
    const float* s_wrel0, const float* s_wroot0, const float* s_b0,
    const float* s_wrel1, const float* s_wroot1, const float* s_b1,
    __half* __restrict__ pn, float* __restrict__ oinitn) {
    float agg[6] = {0.f, 0.f, 0.f, 0.f, 0.f, 0.f};
    const int s = row_start[node];
    const int e = s + cnt[node];
    for (int k = s + q; k < e; k += 32) {
        uint32_t rv[4];
        float    wv[4];
        #pragma unroll
        for (int u = 0; u < 4; ++u) {
            int kk = k + 8 * u;
            int kc = kk < e ? kk : (e - 1);
            rv[u] = rec[kc];
            wv[u] = kk < e ? (float)(rv[u] >> 17) * W_INV : 0.f;
        }
        uint4 raw[4];
        #pragma unroll
        for (int u = 0; u < 4; ++u)
            raw[u] = *(const uint4*)(xpad + (size_t)(rv[u] & 0x1FFFF) * 8);
        #pragma unroll
        for (int u = 0; u < 4; ++u) {
            const __half2* h = (const __half2*)&raw[u];
            float w = wv[u];
            agg[0] += w * __low2float(h[0]);  agg[1] += w * __high2float(h[0]);
            agg[2] += w * __low2float(h[1]);  agg[3] += w * __high2float(h[1]);
            agg[4] += w * __low2float(h[2]);  agg[5] += w * __high2float(h[2]);
        }
    }
    #pragma unroll
    for (int i = 0; i < 6; ++i) {
        agg[i] += __shfl_xor(agg[i], 1);
        agg[i] += __shfl_xor(agg[i], 2);
        agg[i] += __shfl_xor(agg[i], 4);
    }
    uint4 raws = *(const uint4*)(xpad + (size_t)node * 8);
    const __half2* hs = (const __half2*)&raws;
    float xv[6] = { __low2float(hs[0]), __high2float(hs[0]),
                    __low2float(hs[1]), __high2float(hs[1]),
                    __low2float(hs[2]), __high2float(hs[2]) };
    float ov[20];
    #pragma unroll
    for (int j = 0; j < 20; ++j) {
        float o = s_b0[j];
        #pragma unroll
        for (int i = 0; i < 6; ++i)
            o += agg[i] * s_wrel0[i * 20 + j] + xv[i] * s_wroot0[i * 20 + j];
        ov[j] = fmaxf(o, 0.f);
    }
    {
        float pk[2] = {0.f, 0.f};
        #pragma unroll
        for (int kk = 0; kk < 2; ++kk) {
            int k = 2 * q + kk;
            if (k < 15) {
                float sacc = 0.f;
                #pragma unroll
                for (int j = 0; j < 20; ++j) sacc += ov[j] * s_wrel1[j * 15 + k];
                pk[kk] = sacc;
            }
        }
        ((__half2*)(pn + (size_t)node * 16))[q] =
            __halves2half2(__float2half(pk[0]), __float2half(pk[1]));
    }
    #pragma unroll
    for (int kk = 0; kk < 2; ++kk) {
        int k = q + kk * 8;
        if (k < 15) {
            float sacc = s_b1[k];
            #pragma unroll
            for (int j = 0; j < 20; ++j) sacc += ov[j] * s_wroot1[j * 15 + k];
            oinitn[(size_t)node * 15 + k] = sacc;
        }
    }
}

template<int DOUT, int SPH, int NDOUT, int NSPH, bool LAST>
__device__ __forceinline__ void gather_body(
    int node, int q,
    const __half* __restrict__ p, const float* __restrict__ oinit,
    const uint32_t* __restrict__ rec,
    const int* __restrict__ row_start, const int* __restrict__ cnt,
    const float* s_wrel, const float* s_wroot, const float* s_b,
    __half* __restrict__ pn, float* __restrict__ oinitn,
    float* __restrict__ out) {
    float af[SPH];
    #pragma unroll
    for (int i = 0; i < SPH; ++i) af[i] = 0.f;

    const int s = row_start[node];
    const int e = s + cnt[node];
    constexpr int NR = (SPH >= 8) ? SPH / 8 : 1;
    for (int k = s + q; k < e; k += 32) {
        uint32_t rv[4];
        float    wv[4];
        #pragma unroll
        for (int u = 0; u < 4; ++u) {
            int kk = k + 8 * u;
            int kc = kk < e ? kk : (e - 1);
            rv[u] = rec[kc];
            wv[u] = kk < e ? (float)(rv[u] >> 17) * W_INV : 0.f;
        }
        if constexpr (SPH >= 8) {
            uint4 raw[4 * NR];
            #pragma unroll
            for (int u = 0; u < 4; ++u) {
                const uint4* ps = (const uint4*)(p + (size_t)(rv[u] & 0x1FFFF) * SPH);
                #pragma unroll
                for (int v = 0; v < NR; ++v) raw[u * NR + v] = ps[v];
            }
            #pragma unroll
            for (int u = 0; u < 4; ++u) {
                float w = wv[u];
                #pragma unroll
                for (int v = 0; v < NR; ++v) {
                    const __half2* h = (const __half2*)&raw[u * NR + v];
                    #pragma unroll
                    for (int jj = 0; jj < 4; ++jj) {
                        af[v * 8 + 2 * jj]     += w * __low2float(h[jj]);
                        af[v * 8 + 2 * jj + 1] += w * __high2float(h[jj]);
                    }
                }
            }
        } else {
            uint32_t raw[4];
            #pragma unroll
            for (int u = 0; u < 4; ++u)
                raw[u] = *(const uint32_t*)(p + (size_t)(rv[u] & 0x1FFFF) * SPH);
            #pragma unroll
            for (int u = 0; u < 4; ++u) {
                __half2 h = *(const __half2*)&raw[u];
                af[0] += wv[u] * __low2float(h);
                af[1] += wv[u] * __high2float(h);
            }
        }
    }
    #pragma unroll
    for (int i = 0; i < SPH; ++i) {
        af[i] += __shfl_xor(af[i], 1);
        af[i] += __shfl_xor(af[i], 2);
        af[i] += __shfl_xor(af[i], 4);
    }

    if constexpr (LAST) {
        if (q == 0) {
            float o0 = af[0] + oinit[(size_t)node * 2 + 0];
            float o1 = af[1] + oinit[(size_t)node * 2 + 1];
            float m = fmaxf(o0, o1);
            float e0 = __expf(o0 - m), e1 = __expf(o1 - m);
            float inv = 1.f / (e0 + e1);
            out[(size_t)node * 2 + 0] = e0 * inv;
            out[(size_t)node * 2 + 1] = e1 * inv;
        }
    } else {
        float ov[DOUT];
        #pragma unroll
        for (int j = 0; j < DOUT; ++j)
            ov[j] = fmaxf(af[j] + oinit[(size_t)node * DOUT + j], 0.f);

        if (q < NSPH / 2) {
            float pk[2] = {0.f, 0.f};
            #pragma unroll
            for (int kk = 0; kk < 2; ++kk) {
                int k = 2 * q + kk;
                if (k < NDOUT) {
                    float sacc = 0.f;
                    #pragma unroll
                    for (int j = 0; j < DOUT; ++j) sacc += ov[j] * s_wrel[j * NDOUT + k];
                    pk[kk] = sacc;
                }
            }
            ((__half2*)(pn + (size_t)node * NSPH))[q] =
                __halves2half2(__float2half(pk[0]), __float2half(pk[1]));
        }
        #pragma unroll
        for (int kk = 0; kk < 2; ++kk) {
            int k = q + kk * 8;
            if (k < NDOUT) {
                float sacc = s_b[k];
                #pragma unroll
                for (int j = 0; j < DOUT; ++j) sacc += ov[j] * s_wroot[j * NDOUT + k];
                oinitn[(size_t)node * NDOUT + k] = sacc;
            }
        }
    }
}

__global__ void __launch_bounds__(256, 4) layers_kernel(LayerArgs a) {
    __shared__ float s_wrel0[120], s_wroot0[120], s_b0[20];
    __shared__ float s_wreln[300], s_wrootn[300], s_bn[15];
    __shared__ int s_g;
    const int tid = threadIdx.x;

    // stage 0 weights: w0 pair + w1 projection pair
    for (int t = tid; t < 120; t += 256) { s_wrel0[t] = a.wrel0[t]; s_wroot0[t] = a.wroot0[t]; }
    for (int t = tid; t < 300; t += 256) { s_wreln[t] = a.wrel1[t]; s_wrootn[t] = a.wroot1[t]; }
    if (tid < 20) s_b0[tid] = a.brel0[tid];
    if (tid < 15) s_bn[tid] = a.brel1[tid];
    __syncthreads();
    for (;;) {
        if (tid == 0) s_g = atomicAdd(&a.sync_ws[8], 1);
        __syncthreads();
        int g = s_g;
        __syncthreads();
        if (g >= GN8) break;
        int t = g * 256 + tid;
        layer0_body(t >> 3, t & 7, a.xpad, a.rec, a.row_start, a.cnt,
                    s_wrel0, s_wroot0, s_b0, s_wreln, s_wrootn, s_bn, a.pA, a.oA);
    }
    gsync(a.sync_ws, 0);

    // stage 1: agg p1 [15,SPH16] -> p2 [10,SPH16] (wrel2: 15x10)
    for (int t = tid; t < 150; t += 256) { s_wreln[t] = a.wrel2[t]; s_wrootn[t] = a.wroot2[t]; }
    if (tid < 10) s_bn[tid] = a.brel2[tid];
    __syncthreads();
    for (;;) {
        if (tid == 0) s_g = atomicAdd(&a.sync_ws[9], 1);
        __syncthreads();
        int g = s_g;
        __syncthreads();
        if (g >= GN8) break;
        int t = g * 256 + tid;
        gather_body<15, 16, 10, 16, false>(t >> 3, t & 7, a.pA, a.oA, a.rec,
            a.row_start, a.cnt, s_wreln, s_wrootn, s_bn, a.pB, a.oB, nullptr);
    }
    gsync(a.sync_ws, 1);

    // stage 2: agg p2 [10,SPH16] -> p3 [5,SPH8] (wrel3: 10x5)
    for (int t = tid; t < 50; t += 256) { s_wreln[t] = a.wrel3[t]; s_wrootn[t] = a.wroot3[t]; }
    if (tid < 5) s_bn[tid] = a.brel3[tid];
    __syncthreads();
    for (;;) {
        if (tid == 0) s_g = atomicAdd(&a.sync_ws[10], 1);
        __syncthreads();
        int g = s_g;
        __syncthreads();
        if (g >= GN8) break;
        int t = g * 256 + tid;
        gather_body<10, 16, 5, 8, false>(t >> 3, t & 7, a.pB, a.oB, a.rec,
            a.row_start, a.cnt, s_wreln, s_wrootn, s_bn, a.pA, a.oA, nullptr);
    }
    gsync(a.sync_ws, 2);

    // stage 3: agg p3 [5,SPH8] -> p4 [2,SPH2] (wrel4: 5x2)
    for (int t = tid; t < 10; t += 256) { s_wreln[t] = a.wrel4[t]; s_wrootn[t] = a.wroot4[t]; }
    if (tid < 2) s_bn[tid] = a.brel4[tid];
    __syncthreads();
    for (;;) {
        if (tid == 0) s_g = atomicAdd(&a.sync_ws[11], 1);
        __syncthreads();
        int g = s_g;
        __syncthreads();
        if (g >= GN8) break;
        int t = g * 256 + tid;
        gather_body<5, 8, 2, 2, false>(t >> 3, t & 7, a.pA, a.oA, a.rec,
            a.row_start, a.cnt, s_wreln, s_wrootn, s_bn, a.pB, a.oB, nullptr);
    }
    gsync(a.sync_ws, 3);

    // stage 4: agg p4 [2,SPH2] -> softmax -> out
    for (;;) {
        if (tid == 0) s_g = atomicAdd(&a.sync_ws[12], 1);
        __syncthreads();
        int g = s_g;
        __syncthreads();
        if (g >= GN8) break;
        int t = g * 256 + tid;
        gather_body<2, 2, 0, 0, true>(t >> 3, t & 7, a.pB, a.oB, a.rec,
            a.row_start, a.cnt, s_wreln, s_wrootn, s_bn, nullptr, nullptr, a.out);
    }
}

// ---------------------------------------------------------------------------

extern "C" void kernel_launch(void* const* d_in, const int* in_sizes, int n_in,
                              void* d_out, int out_size, void* d_ws, size_t ws_size,
                              hipStream_t stream) {
    const float* x  = (const float*)d_in[0];
    const int*   ei = (const int*)d_in[1];
    const float* ew = (const float*)d_in[2];
    const float* wrel[5]  = { (const float*)d_in[3], (const float*)d_in[6],
                              (const float*)d_in[9], (const float*)d_in[12],
                              (const float*)d_in[15] };
    const float* brel[5]  = { (const float*)d_in[4], (const float*)d_in[7],
                              (const float*)d_in[10], (const float*)d_in[13],
                              (const float*)d_in[16] };
    const float* wroot[5] = { (const float*)d_in[5], (const float*)d_in[8],
                              (const float*)d_in[11], (const float*)d_in[14],
                              (const float*)d_in[17] };

    char* ws = (char*)d_ws;
    size_t off = 0;
    auto alloc = [&](size_t bytes) -> void* {
        void* ptr = ws + off;
        off += (bytes + 255) & ~(size_t)255;
        return ptr;
    };
    // regionA: rec1 during sort (25.6 MB); p/oinit ping-pong during layers
    char*     regionA   = (char*)alloc((size_t)N_EDGES * 8);
    uint2*    rec1      = (uint2*)regionA;
    __half*   pA        = (__half*)regionA;                              // 3.2 MB
    __half*   pB        = (__half*)(regionA + (size_t)4  * 1024 * 1024); // 3.2 MB
    float*    oA        = (float*)(regionA + (size_t)8  * 1024 * 1024);  // 6 MB
    float*    oB        = (float*)(regionA + (size_t)16 * 1024 * 1024);  // 6 MB
    uint32_t* rec2      = (uint32_t*)alloc((size_t)N_EDGES * 4);         // 12.8 MB
    __half*   xpad      = (__half*)alloc((size_t)N_NODES * 8 * 2);       // 1.6 MB
    int*      hist_g    = (int*)alloc((size_t)NCH_H * NB * 4);           // 3.2 MB
    int*      off_g     = (int*)alloc((size_t)NCH_H * NB * 4);           // 3.2 MB
    int*      tot       = (int*)alloc((size_t)NB * 4);
    int*      bstart    = (int*)alloc((size_t)NB * 4);
    int*      row_start = (int*)alloc((size_t)N_NODES * 4);
    int*      cntb      = (int*)alloc((size_t)N_NODES * 4);
    int*      sync_ws   = (int*)alloc(64 * 4);

    const int* srcv = ei;            // edge_index row 0
    const int* dstv = ei + N_EDGES;  // edge_index row 1

    hist_kernel     <<<NCH_H, BLOCK, 0, stream>>>(dstv, hist_g, x, xpad);
    chunkscan_kernel<<<(NB + 3) / 4, BLOCK, 0, stream>>>(hist_g, off_g, tot);
    scan_kernel     <<<1, SCAN_T, 0, stream>>>(tot, bstart, sync_ws);
    scatter1_kernel <<<NCH_S, BS1, 0, stream>>>(srcv, dstv, ew, bstart, off_g, hist_g, rec1);
    scatter2_kernel <<<NB, BS2, 0, stream>>>(rec1, bstart, tot, rec2, row_start, cntb);

    LayerArgs la;
    la.xpad = xpad; la.rec = rec2; la.row_start = row_start; la.cnt = cntb;
    la.wrel0 = wrel[0]; la.brel0 = brel[0]; la.wroot0 = wroot[0];
    la.wrel1 = wrel[1]; la.brel1 = brel[1]; la.wroot1 = wroot[1];
    la.wrel2 = wrel[2]; la.brel2 = brel[2]; la.wroot2 = wroot[2];
    la.wrel3 = wrel[3]; la.brel3 = brel[3]; la.wroot3 = wroot[3];
    la.wrel4 = wrel[4]; la.brel4 = brel[4]; la.wroot4 = wroot[4];
    la.pA = pA; la.pB = pB; la.oA = oA; la.oB = oB;
    la.out = (float*)d_out;
    la.sync_ws = sync_ws;

    layers_kernel<<<LGRID, 256, 0, stream>>>(la);
}

// Round 6
// 1119.417 us; speedup vs baseline: 1.4028x; 1.4028x over previous
//
#include <hip/hip_runtime.h>
#include <hip/hip_fp16.h>
#include <stdint.h>

#define N_NODES 100000
#define N_EDGES 3200000
#define BN      128                   // nodes per dst-bucket
#define NB      782                   // ceil(N_NODES / BN)
// histogram granularity (fine)
#define NCH_H   1024
#define CH_H    (N_EDGES / NCH_H)     // 3125
#define CPL     (NCH_H / 64)          // 16 chunks per lane in chunkscan
#define PAD_PER 98                    // nodes padded per hist block
// scatter granularity: 512 chunks -> 2 resident blocks/CU
#define NCH_S   512
#define CH_S    (N_EDGES / NCH_S)     // 6250
#define FPS     (NCH_H / NCH_S)       // 2 fine chunks per scatter chunk
#define BS1     1024                  // scatter1 block size
#define S1_IT   ((CH_S + BS1 - 1) / BS1)  // 7
#define BS2     512                   // scatter2 block size
#define S2_CAP  4608                  // scatter2 LDS stage capacity (>= max bucket n)
#define R2IT    9                     // scatter2 reg-cache depth (9*512=4608 >= max bucket)
#define BLOCK   256
#define GN8     3125                  // node-groups of 32 nodes (256 thr, 8 lanes/node)
#define LGRID   1024                  // fused layers grid: 4 blocks/CU, all resident
#define W_SCALE 32767.0f
#define W_INV   (1.0f / 32767.0f)

// ---------------------------------------------------------------------------
// Stage 1: per-subchunk bucket histogram + fused x->fp16 padding
// ---------------------------------------------------------------------------
__global__ void hist_kernel(const int* __restrict__ dst, int* __restrict__ hist_g,
                            const float* __restrict__ x, __half* __restrict__ xpad) {
    __shared__ int h[NB];
    for (int b = threadIdx.x; b < NB; b += BLOCK) h[b] = 0;
    {
        int i = blockIdx.x * PAD_PER + threadIdx.x;
        if (threadIdx.x < PAD_PER && i < N_NODES) {
            const float* xr = x + (size_t)i * 6;
            __half2 hh[4];
            hh[0] = __halves2half2(__float2half(xr[0]), __float2half(xr[1]));
            hh[1] = __halves2half2(__float2half(xr[2]), __float2half(xr[3]));
            hh[2] = __halves2half2(__float2half(xr[4]), __float2half(xr[5]));
            hh[3] = __halves2half2(__float2half(0.f),   __float2half(0.f));
            *(uint4*)(xpad + (size_t)i * 8) = *(uint4*)hh;
        }
    }
    __syncthreads();
    const int c  = blockIdx.x;
    const int k0 = c * CH_H;
    for (int k = threadIdx.x; k < CH_H; k += BLOCK)
        atomicAdd(&h[dst[k0 + k] >> 7], 1);
    __syncthreads();
    for (int b = threadIdx.x; b < NB; b += BLOCK)
        hist_g[c * NB + b] = h[b];
}

// ---------------------------------------------------------------------------
// Stage 2a: per-bucket exclusive scan over the 1024 subchunk counts
// ---------------------------------------------------------------------------
__global__ void chunkscan_kernel(const int* __restrict__ hist_g,
                                 int* __restrict__ off_g, int* __restrict__ tot) {
    int w    = (blockIdx.x * blockDim.x + threadIdx.x) >> 6;
    int lane = threadIdx.x & 63;
    if (w >= NB) return;
    int v[CPL];
    int ls = 0;
    const int cbase = lane * CPL;
    #pragma unroll
    for (int i = 0; i < CPL; ++i) { v[i] = hist_g[(cbase + i) * NB + w]; ls += v[i]; }
    int run = ls;
    #pragma unroll
    for (int d = 1; d < 64; d <<= 1) {
        int u = __shfl_up(run, d);
        if (lane >= d) run += u;
    }
    int acc = run - ls;
    #pragma unroll
    for (int i = 0; i < CPL; ++i) { off_g[(cbase + i) * NB + w] = acc; acc += v[i]; }
    if (lane == 63) tot[w] = acc;
}

// ---------------------------------------------------------------------------
// Stage 2b: exclusive scan of NB bucket totals (one wg) + zero the padded
// barrier slots used by the fused layers kernel (slots at sync_ws[64*s]).
// ---------------------------------------------------------------------------
#define SCAN_T   1024
__global__ void scan_kernel(const int* __restrict__ cnt, int* __restrict__ bstart,
                            int* __restrict__ sync_ws) {
    __shared__ int part[SCAN_T];
    int t = threadIdx.x;
    if (t < 512) sync_ws[t] = 0;
    int v = (t < NB) ? cnt[t] : 0;
    part[t] = v;
    __syncthreads();
    for (int off = 1; off < SCAN_T; off <<= 1) {
        int u = (t >= off) ? part[t - off] : 0;
        __syncthreads();
        part[t] += u;
        __syncthreads();
    }
    if (t < NB) bstart[t] = part[t] - v;
}

// ---------------------------------------------------------------------------
// Stage 3: scatter pass 1 — full-record LDS stage, all-coalesced global IO.
// ---------------------------------------------------------------------------
__global__ void __launch_bounds__(BS1)
scatter1_kernel(const int* __restrict__ src, const int* __restrict__ dst,
                const float* __restrict__ w,
                const int* __restrict__ bstart, const int* __restrict__ off_g,
                const int* __restrict__ hist_g,
                uint2* __restrict__ rec1) {
    __shared__ uint2 stage[CH_S];      // 50000 B: full records
    __shared__ int h[NB];
    __shared__ int delta[NB];
    __shared__ int wtot[BS1 / 64];

    const int c  = blockIdx.x;
    const int k0 = c * CH_S;
    const int t  = threadIdx.x;

    // phase 0: issue all chunk loads (coalesced) before the scan phases
    int      dv[S1_IT];
    uint32_t sv[S1_IT];
    float    wv[S1_IT];
    #pragma unroll
    for (int i = 0; i < S1_IT; ++i) {
        int k = t + i * BS1;
        if (k < CH_S) {
            dv[i] = dst[k0 + k];
            sv[i] = (uint32_t)src[k0 + k];
            wv[i] = w[k0 + k];
        }
    }

    // phase 1: local bucket counts from hist_g (no dst pass, no atomics)
    for (int b = t; b < NB; b += BS1) {
        int s = 0;
        #pragma unroll
        for (int f = 0; f < FPS; ++f)
            s += hist_g[(size_t)(FPS * c + f) * NB + b];
        h[b] = s;
    }
    __syncthreads();

    // phase 2: block scan of h -> cursor start (in h) + delta
    {
        const int base = t * 2;          // 2048 >= NB
        int v[2], ls = 0;
        #pragma unroll
        for (int i = 0; i < 2; ++i) {
            int idx = base + i;
            v[i] = (idx < NB) ? h[idx] : 0;
            ls += v[i];
        }
        int lane = t & 63, wvi = t >> 6;
        int run = ls;
        #pragma unroll
        for (int d = 1; d < 64; d <<= 1) {
            int u = __shfl_up(run, d);
            if (lane >= d) run += u;
        }
        if (lane == 63) wtot[wvi] = run;
        __syncthreads();
        int wexcl = 0;
        for (int i = 0; i < wvi; ++i) wexcl += wtot[i];
        int excl = wexcl + run - ls;
        #pragma unroll
        for (int i = 0; i < 2; ++i) {
            int idx = base + i;
            if (idx < NB) {
                int gb = bstart[idx] + off_g[(size_t)(FPS * c) * NB + idx];
                h[idx]     = excl;
                delta[idx] = gb - excl;
                excl += v[i];
            }
        }
    }
    __syncthreads();

    // phase 3: full-record scatter into LDS stage (LDS cursors)
    #pragma unroll
    for (int i = 0; i < S1_IT; ++i) {
        int k = t + i * BS1;
        if (k < CH_S) {
            int d = dv[i];
            int b = d >> 7;
            int pos = atomicAdd(&h[b], 1);
            uint32_t w15 = (uint32_t)__float2uint_rn(wv[i] * W_SCALE);
            uint2 r;
            r.x = sv[i] | ((uint32_t)(d & 127) << 17);
            r.y = w15 | ((uint32_t)b << 15);
            stage[pos] = r;
        }
    }
    __syncthreads();

    // phase 4: sequential LDS read -> coalesced global store (runs of ~8)
    #pragma unroll
    for (int i = 0; i < S1_IT; ++i) {
        int k = t + i * BS1;
        if (k < CH_S) {
            uint2 r = stage[k];
            int b = (int)(r.y >> 15);
            rec1[delta[b] + k] = r;
        }
    }
}

// ---------------------------------------------------------------------------
// Stage 4: scatter pass 2 — node-sort each 128-node bucket through an LDS
// stage. rec1 register-cached across the two passes.
// Emits 4 B rec2 = src(17) | w15(15)<<17.
// ---------------------------------------------------------------------------
__global__ void __launch_bounds__(BS2)
scatter2_kernel(const uint2* __restrict__ rec1,
                const int* __restrict__ bstart, const int* __restrict__ tot,
                uint32_t* __restrict__ rec2,
                int* __restrict__ row_start, int* __restrict__ cnt) {
    __shared__ int h[BN];
    __shared__ int cur[BN];
    __shared__ int wtot2[2];
    __shared__ uint32_t stage[S2_CAP];
    const int b  = blockIdx.x;
    const int s0 = bstart[b];
    const int n  = tot[b];
    const int t  = threadIdx.x;
    if (t < BN) h[t] = 0;
    __syncthreads();

    uint2 rv[R2IT];
    #pragma unroll
    for (int i = 0; i < R2IT; ++i) {
        int k = t + i * BS2;
        uint2 r = (k < n) ? rec1[s0 + k] : make_uint2(0u, 0u);
        rv[i] = r;
        if (k < n) atomicAdd(&h[r.x >> 17], 1);
    }
    for (int k = t + R2IT * BS2; k < n; k += BS2)
        atomicAdd(&h[rec1[s0 + k].x >> 17], 1);
    __syncthreads();

    // two-wave exclusive scan over BN=128 counters
    int v = 0, run = 0;
    if (t < BN) {
        v = h[t];
        run = v;
        int lane = t & 63;
        #pragma unroll
        for (int d = 1; d < 64; d <<= 1) {
            int u = __shfl_up(run, d);
            if (lane >= d) run += u;
        }
        if (lane == 63) wtot2[t >> 6] = run;
    }
    __syncthreads();
    if (t < BN) {
        int excl = run - v + ((t >= 64) ? wtot2[0] : 0);
        cur[t] = excl;
        int node = b * BN + t;
        if (node < N_NODES) { row_start[node] = s0 + excl; cnt[node] = v; }
    }
    __syncthreads();

    #pragma unroll
    for (int i = 0; i < R2IT; ++i) {
        int k = t + i * BS2;
        if (k < n) {
            uint2 r = rv[i];
            int dl = (int)(r.x >> 17);
            uint32_t r2 = (r.x & 0x1FFFF) | ((r.y & 0x7FFF) << 17);
            int pos = atomicAdd(&cur[dl], 1);
            if (pos < S2_CAP) stage[pos] = r2;
            else              rec2[s0 + pos] = r2;
        }
    }
    for (int k = t + R2IT * BS2; k < n; k += BS2) {
        uint2 r = rec1[s0 + k];
        int dl = (int)(r.x >> 17);
        uint32_t r2 = (r.x & 0x1FFFF) | ((r.y & 0x7FFF) << 17);
        int pos = atomicAdd(&cur[dl], 1);
        if (pos < S2_CAP) stage[pos] = r2;
        else              rec2[s0 + pos] = r2;
    }
    __syncthreads();
    for (int i = t; i < n && i < S2_CAP; i += BS2)
        rec2[s0 + i] = stage[i];
}

// ---------------------------------------------------------------------------
// Fused layer pipeline: layer0 + 4 gather stages in ONE plain-launched
// persistent kernel. R5 post-mortem: the 10x stretch was the per-THREAD
// __threadfence() at each barrier (1.3M agent-scope L2 wb/inv ops) plus
// steal/spin traffic on one cacheline. Fixes: tid0-only fences (sound:
// stores are L2-resident at __syncthreads; one wbl2/inv per block covers
// the shared XCD L2 + the block's CU L1), relaxed polls with s_sleep
// backoff, static balanced partition (no steal atomics), 256B-padded
// barrier slots. Residency: launch_bounds(256,4) caps VGPR at 128,
// LDS 3.5KB -> 4 blocks/CU, grid 1024 = 4*256 CUs all co-resident.
// ---------------------------------------------------------------------------
struct LayerArgs {
    const __half* xpad;
    const uint32_t* rec;
    const int* row_start;
    const int* cnt;
    const float* wrel0; const float* brel0; const float* wroot0;
    const float* wrel1; const float* brel1; const float* wroot1;
    const float* wrel2; const float* brel2; const float* wroot2;
    const float* wrel3; const float* brel3; const float* wroot3;
    const float* wrel4; const float* brel4; const float* wroot4;
    __half* pA; __half* pB;
    float* oA; float* oB;
    float* out;
    int* sync_ws;   // barrier slot s at sync_ws[64 + 64*s], 256B apart
};

__device__ __forceinline__ void gsync(int* slot) {
    __syncthreads();   // all block stores drained (vmcnt) and visible in L2
    if (threadIdx.x == 0) {
        __threadfence();   // release: write back this XCD's L2 (cross-XCD G16)
        __hip_atomic_fetch_add(slot, 1, __ATOMIC_RELAXED, __HIP_MEMORY_SCOPE_AGENT);
        while (__hip_atomic_load(slot, __ATOMIC_RELAXED, __HIP_MEMORY_SCOPE_AGENT) < LGRID)
            __builtin_amdgcn_s_sleep(2);
        __threadfence();   // acquire: invalidate CU L1 + XCD L2
    }
    __syncthreads();
}

__device__ __forceinline__ void layer0_body(
    int node, int q,
    const __half* __restrict__ xpad, const uint32_t* __restrict__ rec,
    const int* __restrict__ row_start, const int* __restrict__ cnt,
    const float* s_wrel0, const float* s_wroot0, const float* s_b0,
    const float* s_wrel1, const float* s_wroot1, const float* s_b1,
    __half* __restrict__ pn, float* __restrict__ oinitn) {
    float agg[6] = {0.f, 0.f, 0.f, 0.f, 0.f, 0.f};
    const int s = row_start[node];
    const int e = s + cnt[node];
    for (int k = s + q; k < e; k += 32) {
        uint32_t rv[4];
        float    wv[4];
        #pragma unroll
        for (int u = 0; u < 4; ++u) {
            int kk = k + 8 * u;
            int kc = kk < e ? kk : (e - 1);
            rv[u] = rec[kc];
            wv[u] = kk < e ? (float)(rv[u] >> 17) * W_INV : 0.f;
        }
        uint4 raw[4];
        #pragma unroll
        for (int u = 0; u < 4; ++u)
            raw[u] = *(const uint4*)(xpad + (size_t)(rv[u] & 0x1FFFF) * 8);
        #pragma unroll
        for (int u = 0; u < 4; ++u) {
            const __half2* h = (const __half2*)&raw[u];
            float w = wv[u];
            agg[0] += w * __low2float(h[0]);  agg[1] += w * __high2float(h[0]);
            agg[2] += w * __low2float(h[1]);  agg[3] += w * __high2float(h[1]);
            agg[4] += w * __low2float(h[2]);  agg[5] += w * __high2float(h[2]);
        }
    }
    #pragma unroll
    for (int i = 0; i < 6; ++i) {
        agg[i] += __shfl_xor(agg[i], 1);
        agg[i] += __shfl_xor(agg[i], 2);
        agg[i] += __shfl_xor(agg[i], 4);
    }
    uint4 raws = *(const uint4*)(xpad + (size_t)node * 8);
    const __half2* hs = (const __half2*)&raws;
    float xv[6] = { __low2float(hs[0]), __high2float(hs[0]),
                    __low2float(hs[1]), __high2float(hs[1]),
                    __low2float(hs[2]), __high2float(hs[2]) };
    float ov[20];
    #pragma unroll
    for (int j = 0; j < 20; ++j) {
        float o = s_b0[j];
        #pragma unroll
        for (int i = 0; i < 6; ++i)
            o += agg[i] * s_wrel0[i * 20 + j] + xv[i] * s_wroot0[i * 20 + j];
        ov[j] = fmaxf(o, 0.f);
    }
    {
        float pk[2] = {0.f, 0.f};
        #pragma unroll
        for (int kk = 0; kk < 2; ++kk) {
            int k = 2 * q + kk;
            if (k < 15) {
                float sacc = 0.f;
                #pragma unroll
                for (int j = 0; j < 20; ++j) sacc += ov[j] * s_wrel1[j * 15 + k];
                pk[kk] = sacc;
            }
        }
        ((__half2*)(pn + (size_t)node * 16))[q] =
            __halves2half2(__float2half(pk[0]), __float2half(pk[1]));
    }
    #pragma unroll
    for (int kk = 0; kk < 2; ++kk) {
        int k = q + kk * 8;
        if (k < 15) {
            float sacc = s_b1[k];
            #pragma unroll
            for (int j = 0; j < 20; ++j) sacc += ov[j] * s_wroot1[j * 15 + k];
            oinitn[(size_t)node * 15 + k] = sacc;
        }
    }
}

template<int DOUT, int SPH, int NDOUT, int NSPH, bool LAST>
__device__ __forceinline__ void gather_body(
    int node, int q,
    const __half* __restrict__ p, const float* __restrict__ oinit,
    const uint32_t* __restrict__ rec,
    const int* __restrict__ row_start, const int* __restrict__ cnt,
    const float* s_wrel, const float* s_wroot, const float* s_b,
    __half* __restrict__ pn, float* __restrict__ oinitn,
    float* __restrict__ out) {
    float af[SPH];
    #pragma unroll
    for (int i = 0; i < SPH; ++i) af[i] = 0.f;

    const int s = row_start[node];
    const int e = s + cnt[node];
    constexpr int NR = (SPH >= 8) ? SPH / 8 : 1;
    for (int k = s + q; k < e; k += 32) {
        uint32_t rv[4];
        float    wv[4];
        #pragma unroll
        for (int u = 0; u < 4; ++u) {
            int kk = k + 8 * u;
            int kc = kk < e ? kk : (e - 1);
            rv[u] = rec[kc];
            wv[u] = kk < e ? (float)(rv[u] >> 17) * W_INV : 0.f;
        }
        if constexpr (SPH >= 8) {
            uint4 raw[4 * NR];
            #pragma unroll
            for (int u = 0; u < 4; ++u) {
                const uint4* ps = (const uint4*)(p + (size_t)(rv[u] & 0x1FFFF) * SPH);
                #pragma unroll
                for (int v = 0; v < NR; ++v) raw[u * NR + v] = ps[v];
            }
            #pragma unroll
            for (int u = 0; u < 4; ++u) {
                float w = wv[u];
                #pragma unroll
                for (int v = 0; v < NR; ++v) {
                    const __half2* h = (const __half2*)&raw[u * NR + v];
                    #pragma unroll
                    for (int jj = 0; jj < 4; ++jj) {
                        af[v * 8 + 2 * jj]     += w * __low2float(h[jj]);
                        af[v * 8 + 2 * jj + 1] += w * __high2float(h[jj]);
                    }
                }
            }
        } else {
            uint32_t raw[4];
            #pragma unroll
            for (int u = 0; u < 4; ++u)
                raw[u] = *(const uint32_t*)(p + (size_t)(rv[u] & 0x1FFFF) * SPH);
            #pragma unroll
            for (int u = 0; u < 4; ++u) {
                __half2 h = *(const __half2*)&raw[u];
                af[0] += wv[u] * __low2float(h);
                af[1] += wv[u] * __high2float(h);
            }
        }
    }
    #pragma unroll
    for (int i = 0; i < SPH; ++i) {
        af[i] += __shfl_xor(af[i], 1);
        af[i] += __shfl_xor(af[i], 2);
        af[i] += __shfl_xor(af[i], 4);
    }

    if constexpr (LAST) {
        if (q == 0) {
            float o0 = af[0] + oinit[(size_t)node * 2 + 0];
            float o1 = af[1] + oinit[(size_t)node * 2 + 1];
            float m = fmaxf(o0, o1);
            float e0 = __expf(o0 - m), e1 = __expf(o1 - m);
            float inv = 1.f / (e0 + e1);
            out[(size_t)node * 2 + 0] = e0 * inv;
            out[(size_t)node * 2 + 1] = e1 * inv;
        }
    } else {
        float ov[DOUT];
        #pragma unroll
        for (int j = 0; j < DOUT; ++j)
            ov[j] = fmaxf(af[j] + oinit[(size_t)node * DOUT + j], 0.f);

        if (q < NSPH / 2) {
            float pk[2] = {0.f, 0.f};
            #pragma unroll
            for (int kk = 0; kk < 2; ++kk) {
                int k = 2 * q + kk;
                if (k < NDOUT) {
                    float sacc = 0.f;
                    #pragma unroll
                    for (int j = 0; j < DOUT; ++j) sacc += ov[j] * s_wrel[j * NDOUT + k];
                    pk[kk] = sacc;
                }
            }
            ((__half2*)(pn + (size_t)node * NSPH))[q] =
                __halves2half2(__float2half(pk[0]), __float2half(pk[1]));
        }
        #pragma unroll
        for (int kk = 0; kk < 2; ++kk) {
            int k = q + kk * 8;
            if (k < NDOUT) {
                float sacc = s_b[k];
                #pragma unroll
                for (int j = 0; j < DOUT; ++j) sacc += ov[j] * s_wroot[j * NDOUT + k];
                oinitn[(size_t)node * NDOUT + k] = sacc;
            }
        }
    }
}

__global__ void __launch_bounds__(256, 4) layers_kernel(LayerArgs a) {
    __shared__ float s_wrel0[120], s_wroot0[120], s_b0[20];
    __shared__ float s_wreln[300], s_wrootn[300], s_bn[15];
    const int tid = threadIdx.x;

    // static balanced partition of GN8 groups over LGRID blocks
    const int qn = GN8 / LGRID;                     // 3
    const int rn = GN8 % LGRID;                     // 53
    const int bx = blockIdx.x;
    const int g0   = bx * qn + (bx < rn ? bx : rn);
    const int gend = g0 + qn + (bx < rn ? 1 : 0);

    // stage 0 weights: w0 pair + w1 projection pair
    for (int t = tid; t < 120; t += 256) { s_wrel0[t] = a.wrel0[t]; s_wroot0[t] = a.wroot0[t]; }
    for (int t = tid; t < 300; t += 256) { s_wreln[t] = a.wrel1[t]; s_wrootn[t] = a.wroot1[t]; }
    if (tid < 20) s_b0[tid] = a.brel0[tid];
    if (tid < 15) s_bn[tid] = a.brel1[tid];
    __syncthreads();
    for (int g = g0; g < gend; ++g) {
        int t = g * 256 + tid;
        layer0_body(t >> 3, t & 7, a.xpad, a.rec, a.row_start, a.cnt,
                    s_wrel0, s_wroot0, s_b0, s_wreln, s_wrootn, s_bn, a.pA, a.oA);
    }
    gsync(a.sync_ws + 64);

    // stage 1: agg p1 [15,SPH16] -> p2 [10,SPH16] (wrel2: 15x10)
    for (int t = tid; t < 150; t += 256) { s_wreln[t] = a.wrel2[t]; s_wrootn[t] = a.wroot2[t]; }
    if (tid < 10) s_bn[tid] = a.brel2[tid];
    __syncthreads();
    for (int g = g0; g < gend; ++g) {
        int t = g * 256 + tid;
        gather_body<15, 16, 10, 16, false>(t >> 3, t & 7, a.pA, a.oA, a.rec,
            a.row_start, a.cnt, s_wreln, s_wrootn, s_bn, a.pB, a.oB, nullptr);
    }
    gsync(a.sync_ws + 128);

    // stage 2: agg p2 [10,SPH16] -> p3 [5,SPH8] (wrel3: 10x5)
    for (int t = tid; t < 50; t += 256) { s_wreln[t] = a.wrel3[t]; s_wrootn[t] = a.wroot3[t]; }
    if (tid < 5) s_bn[tid] = a.brel3[tid];
    __syncthreads();
    for (int g = g0; g < gend; ++g) {
        int t = g * 256 + tid;
        gather_body<10, 16, 5, 8, false>(t >> 3, t & 7, a.pB, a.oB, a.rec,
            a.row_start, a.cnt, s_wreln, s_wrootn, s_bn, a.pA, a.oA, nullptr);
    }
    gsync(a.sync_ws + 192);

    // stage 3: agg p3 [5,SPH8] -> p4 [2,SPH2] (wrel4: 5x2)
    for (int t = tid; t < 10; t += 256) { s_wreln[t] = a.wrel4[t]; s_wrootn[t] = a.wroot4[t]; }
    if (tid < 2) s_bn[tid] = a.brel4[tid];
    __syncthreads();
    for (int g = g0; g < gend; ++g) {
        int t = g * 256 + tid;
        gather_body<5, 8, 2, 2, false>(t >> 3, t & 7, a.pA, a.oA, a.rec,
            a.row_start, a.cnt, s_wreln, s_wrootn, s_bn, a.pB, a.oB, nullptr);
    }
    gsync(a.sync_ws + 256);

    // stage 4: agg p4 [2,SPH2] -> softmax -> out
    for (int g = g0; g < gend; ++g) {
        int t = g * 256 + tid;
        gather_body<2, 2, 0, 0, true>(t >> 3, t & 7, a.pB, a.oB, a.rec,
            a.row_start, a.cnt, s_wreln, s_wrootn, s_bn, nullptr, nullptr, a.out);
    }
}

// ---------------------------------------------------------------------------

extern "C" void kernel_launch(void* const* d_in, const int* in_sizes, int n_in,
                              void* d_out, int out_size, void* d_ws, size_t ws_size,
                              hipStream_t stream) {
    const float* x  = (const float*)d_in[0];
    const int*   ei = (const int*)d_in[1];
    const float* ew = (const float*)d_in[2];
    const float* wrel[5]  = { (const float*)d_in[3], (const float*)d_in[6],
                              (const float*)d_in[9], (const float*)d_in[12],
                              (const float*)d_in[15] };
    const float* brel[5]  = { (const float*)d_in[4], (const float*)d_in[7],
                              (const float*)d_in[10], (const float*)d_in[13],
                              (const float*)d_in[16] };
    const float* wroot[5] = { (const float*)d_in[5], (const float*)d_in[8],
                              (const float*)d_in[11], (const float*)d_in[14],
                              (const float*)d_in[17] };

    char* ws = (char*)d_ws;
    size_t off = 0;
    auto alloc = [&](size_t bytes) -> void* {
        void* ptr = ws + off;
        off += (bytes + 255) & ~(size_t)255;
        return ptr;
    };
    // regionA: rec1 during sort (25.6 MB); p/oinit ping-pong during layers
    char*     regionA   = (char*)alloc((size_t)N_EDGES * 8);
    uint2*    rec1      = (uint2*)regionA;
    __half*   pA        = (__half*)regionA;                              // 3.2 MB
    __half*   pB        = (__half*)(regionA + (size_t)4  * 1024 * 1024); // 3.2 MB
    float*    oA        = (float*)(regionA + (size_t)8  * 1024 * 1024);  // 6 MB
    float*    oB        = (float*)(regionA + (size_t)16 * 1024 * 1024);  // 6 MB
    uint32_t* rec2      = (uint32_t*)alloc((size_t)N_EDGES * 4);         // 12.8 MB
    __half*   xpad      = (__half*)alloc((size_t)N_NODES * 8 * 2);       // 1.6 MB
    int*      hist_g    = (int*)alloc((size_t)NCH_H * NB * 4);           // 3.2 MB
    int*      off_g     = (int*)alloc((size_t)NCH_H * NB * 4);           // 3.2 MB
    int*      tot       = (int*)alloc((size_t)NB * 4);
    int*      bstart    = (int*)alloc((size_t)NB * 4);
    int*      row_start = (int*)alloc((size_t)N_NODES * 4);
    int*      cntb      = (int*)alloc((size_t)N_NODES * 4);
    int*      sync_ws   = (int*)alloc(512 * 4);

    const int* srcv = ei;            // edge_index row 0
    const int* dstv = ei + N_EDGES;  // edge_index row 1

    hist_kernel     <<<NCH_H, BLOCK, 0, stream>>>(dstv, hist_g, x, xpad);
    chunkscan_kernel<<<(NB + 3) / 4, BLOCK, 0, stream>>>(hist_g, off_g, tot);
    scan_kernel     <<<1, SCAN_T, 0, stream>>>(tot, bstart, sync_ws);
    scatter1_kernel <<<NCH_S, BS1, 0, stream>>>(srcv, dstv, ew, bstart, off_g, hist_g, rec1);
    scatter2_kernel <<<NB, BS2, 0, stream>>>(rec1, bstart, tot, rec2, row_start, cntb);

    LayerArgs la;
    la.xpad = xpad; la.rec = rec2; la.row_start = row_start; la.cnt = cntb;
    la.wrel0 = wrel[0]; la.brel0 = brel[0]; la.wroot0 = wroot[0];
    la.wrel1 = wrel[1]; la.brel1 = brel[1]; la.wroot1 = wroot[1];
    la.wrel2 = wrel[2]; la.brel2 = brel[2]; la.wroot2 = wroot[2];
    la.wrel3 = wrel[3]; la.brel3 = brel[3]; la.wroot3 = wroot[3];
    la.wrel4 = wrel[4]; la.brel4 = brel[4]; la.wroot4 = wroot[4];
    la.pA = pA; la.pB = pB; la.oA = oA; la.oB = oB;
    la.out = (float*)d_out;
    la.sync_ws = sync_ws;

    layers_kernel<<<LGRID, 256, 0, stream>>>(la);
}

// Round 7
// 279.632 us; speedup vs baseline: 5.6155x; 4.0032x over previous
//
#include <hip/hip_runtime.h>
#include <hip/hip_fp16.h>
#include <stdint.h>

#define N_NODES 100000
#define N_EDGES 3200000
#define BN      128                   // nodes per dst-bucket
#define NB      782                   // ceil(N_NODES / BN)
// histogram granularity (fine)
#define NCH_H   1024
#define CH_H    (N_EDGES / NCH_H)     // 3125
#define CPL     (NCH_H / 64)          // 16 chunks per lane in chunkscan
#define PAD_PER 98                    // nodes padded per hist block
// scatter granularity: 512 chunks -> 2 resident blocks/CU
#define NCH_S   512
#define CH_S    (N_EDGES / NCH_S)     // 6250
#define FPS     (NCH_H / NCH_S)       // 2 fine chunks per scatter chunk
#define BS1     1024                  // scatter1 block size
#define S1_IT   ((CH_S + BS1 - 1) / BS1)  // 7
#define BS2     512                   // scatter2 block size
#define S2_CAP  4608                  // scatter2 LDS stage capacity (>= max bucket n)
#define R2IT    9                     // scatter2 reg-cache depth (9*512=4608 >= max bucket)
#define BLOCK   256
#define W_SCALE 32767.0f
#define W_INV   (1.0f / 32767.0f)

// ---------------------------------------------------------------------------
// Stage 1: per-subchunk bucket histogram + fused x->fp16 padding
// ---------------------------------------------------------------------------
__global__ void hist_kernel(const int* __restrict__ dst, int* __restrict__ hist_g,
                            const float* __restrict__ x, __half* __restrict__ xpad) {
    __shared__ int h[NB];
    for (int b = threadIdx.x; b < NB; b += BLOCK) h[b] = 0;
    {
        int i = blockIdx.x * PAD_PER + threadIdx.x;
        if (threadIdx.x < PAD_PER && i < N_NODES) {
            const float* xr = x + (size_t)i * 6;
            __half2 hh[4];
            hh[0] = __halves2half2(__float2half(xr[0]), __float2half(xr[1]));
            hh[1] = __halves2half2(__float2half(xr[2]), __float2half(xr[3]));
            hh[2] = __halves2half2(__float2half(xr[4]), __float2half(xr[5]));
            hh[3] = __halves2half2(__float2half(0.f),   __float2half(0.f));
            *(uint4*)(xpad + (size_t)i * 8) = *(uint4*)hh;
        }
    }
    __syncthreads();
    const int c  = blockIdx.x;
    const int k0 = c * CH_H;
    for (int k = threadIdx.x; k < CH_H; k += BLOCK)
        atomicAdd(&h[dst[k0 + k] >> 7], 1);
    __syncthreads();
    for (int b = threadIdx.x; b < NB; b += BLOCK)
        hist_g[c * NB + b] = h[b];
}

// ---------------------------------------------------------------------------
// Stage 2a: per-bucket exclusive scan over the 1024 subchunk counts
// ---------------------------------------------------------------------------
__global__ void chunkscan_kernel(const int* __restrict__ hist_g,
                                 int* __restrict__ off_g, int* __restrict__ tot) {
    int w    = (blockIdx.x * blockDim.x + threadIdx.x) >> 6;
    int lane = threadIdx.x & 63;
    if (w >= NB) return;
    int v[CPL];
    int ls = 0;
    const int cbase = lane * CPL;
    #pragma unroll
    for (int i = 0; i < CPL; ++i) { v[i] = hist_g[(cbase + i) * NB + w]; ls += v[i]; }
    int run = ls;
    #pragma unroll
    for (int d = 1; d < 64; d <<= 1) {
        int u = __shfl_up(run, d);
        if (lane >= d) run += u;
    }
    int acc = run - ls;
    #pragma unroll
    for (int i = 0; i < CPL; ++i) { off_g[(cbase + i) * NB + w] = acc; acc += v[i]; }
    if (lane == 63) tot[w] = acc;
}

// ---------------------------------------------------------------------------
// Stage 2b: exclusive scan of NB bucket totals (one wg)
// ---------------------------------------------------------------------------
#define SCAN_T   1024
__global__ void scan_kernel(const int* __restrict__ cnt, int* __restrict__ bstart) {
    __shared__ int part[SCAN_T];
    int t = threadIdx.x;
    int v = (t < NB) ? cnt[t] : 0;
    part[t] = v;
    __syncthreads();
    for (int off = 1; off < SCAN_T; off <<= 1) {
        int u = (t >= off) ? part[t - off] : 0;
        __syncthreads();
        part[t] += u;
        __syncthreads();
    }
    if (t < NB) bstart[t] = part[t] - v;
}

// ---------------------------------------------------------------------------
// Stage 3: scatter pass 1 — full-record LDS stage, all-coalesced global IO.
// (R3-proven: no scattered global loads; w15 quantized here.)
// ---------------------------------------------------------------------------
__global__ void __launch_bounds__(BS1)
scatter1_kernel(const int* __restrict__ src, const int* __restrict__ dst,
                const float* __restrict__ w,
                const int* __restrict__ bstart, const int* __restrict__ off_g,
                const int* __restrict__ hist_g,
                uint2* __restrict__ rec1) {
    __shared__ uint2 stage[CH_S];      // 50000 B: full records
    __shared__ int h[NB];
    __shared__ int delta[NB];
    __shared__ int wtot[BS1 / 64];

    const int c  = blockIdx.x;
    const int k0 = c * CH_S;
    const int t  = threadIdx.x;

    // phase 0: issue all chunk loads (coalesced) before the scan phases
    int      dv[S1_IT];
    uint32_t sv[S1_IT];
    float    wv[S1_IT];
    #pragma unroll
    for (int i = 0; i < S1_IT; ++i) {
        int k = t + i * BS1;
        if (k < CH_S) {
            dv[i] = dst[k0 + k];
            sv[i] = (uint32_t)src[k0 + k];
            wv[i] = w[k0 + k];
        }
    }

    // phase 1: local bucket counts from hist_g (no dst pass, no atomics)
    for (int b = t; b < NB; b += BS1) {
        int s = 0;
        #pragma unroll
        for (int f = 0; f < FPS; ++f)
            s += hist_g[(size_t)(FPS * c + f) * NB + b];
        h[b] = s;
    }
    __syncthreads();

    // phase 2: block scan of h -> cursor start (in h) + delta
    {
        const int base = t * 2;          // 2048 >= NB
        int v[2], ls = 0;
        #pragma unroll
        for (int i = 0; i < 2; ++i) {
            int idx = base + i;
            v[i] = (idx < NB) ? h[idx] : 0;
            ls += v[i];
        }
        int lane = t & 63, wvi = t >> 6;
        int run = ls;
        #pragma unroll
        for (int d = 1; d < 64; d <<= 1) {
            int u = __shfl_up(run, d);
            if (lane >= d) run += u;
        }
        if (lane == 63) wtot[wvi] = run;
        __syncthreads();
        int wexcl = 0;
        for (int i = 0; i < wvi; ++i) wexcl += wtot[i];
        int excl = wexcl + run - ls;
        #pragma unroll
        for (int i = 0; i < 2; ++i) {
            int idx = base + i;
            if (idx < NB) {
                int gb = bstart[idx] + off_g[(size_t)(FPS * c) * NB + idx];
                h[idx]     = excl;
                delta[idx] = gb - excl;
                excl += v[i];
            }
        }
    }
    __syncthreads();

    // phase 3: full-record scatter into LDS stage (LDS cursors)
    #pragma unroll
    for (int i = 0; i < S1_IT; ++i) {
        int k = t + i * BS1;
        if (k < CH_S) {
            int d = dv[i];
            int b = d >> 7;
            int pos = atomicAdd(&h[b], 1);
            uint32_t w15 = (uint32_t)__float2uint_rn(wv[i] * W_SCALE);
            uint2 r;
            r.x = sv[i] | ((uint32_t)(d & 127) << 17);
            r.y = w15 | ((uint32_t)b << 15);
            stage[pos] = r;
        }
    }
    __syncthreads();

    // phase 4: sequential LDS read -> coalesced global store (runs of ~8)
    #pragma unroll
    for (int i = 0; i < S1_IT; ++i) {
        int k = t + i * BS1;
        if (k < CH_S) {
            uint2 r = stage[k];
            int b = (int)(r.y >> 15);
            rec1[delta[b] + k] = r;
        }
    }
}

// ---------------------------------------------------------------------------
// Stage 4: scatter pass 2 — node-sort each 128-node bucket through an LDS
// stage. rec1 register-cached across the two passes. Emits rec2 =
// src(17)|w15(15)<<17 and packed rowcnt[node] = {row_start, cnt} (int2 —
// one 8B load per node in the layer kernels instead of two 4B loads).
// ---------------------------------------------------------------------------
__global__ void __launch_bounds__(BS2)
scatter2_kernel(const uint2* __restrict__ rec1,
                const int* __restrict__ bstart, const int* __restrict__ tot,
                uint32_t* __restrict__ rec2,
                int2* __restrict__ rowcnt) {
    __shared__ int h[BN];
    __shared__ int cur[BN];
    __shared__ int wtot2[2];
    __shared__ uint32_t stage[S2_CAP];
    const int b  = blockIdx.x;
    const int s0 = bstart[b];
    const int n  = tot[b];
    const int t  = threadIdx.x;
    if (t < BN) h[t] = 0;
    __syncthreads();

    uint2 rv[R2IT];
    #pragma unroll
    for (int i = 0; i < R2IT; ++i) {
        int k = t + i * BS2;
        uint2 r = (k < n) ? rec1[s0 + k] : make_uint2(0u, 0u);
        rv[i] = r;
        if (k < n) atomicAdd(&h[r.x >> 17], 1);
    }
    for (int k = t + R2IT * BS2; k < n; k += BS2)
        atomicAdd(&h[rec1[s0 + k].x >> 17], 1);
    __syncthreads();

    // two-wave exclusive scan over BN=128 counters
    int v = 0, run = 0;
    if (t < BN) {
        v = h[t];
        run = v;
        int lane = t & 63;
        #pragma unroll
        for (int d = 1; d < 64; d <<= 1) {
            int u = __shfl_up(run, d);
            if (t >= d && lane >= d) run += u;
        }
        if (lane == 63) wtot2[t >> 6] = run;
    }
    __syncthreads();
    if (t < BN) {
        int excl = run - v + ((t >= 64) ? wtot2[0] : 0);
        cur[t] = excl;
        int node = b * BN + t;
        if (node < N_NODES) rowcnt[node] = make_int2(s0 + excl, v);
    }
    __syncthreads();

    #pragma unroll
    for (int i = 0; i < R2IT; ++i) {
        int k = t + i * BS2;
        if (k < n) {
            uint2 r = rv[i];
            int dl = (int)(r.x >> 17);
            uint32_t r2 = (r.x & 0x1FFFF) | ((r.y & 0x7FFF) << 17);
            int pos = atomicAdd(&cur[dl], 1);
            if (pos < S2_CAP) stage[pos] = r2;
            else              rec2[s0 + pos] = r2;
        }
    }
    for (int k = t + R2IT * BS2; k < n; k += BS2) {
        uint2 r = rec1[s0 + k];
        int dl = (int)(r.x >> 17);
        uint32_t r2 = (r.x & 0x1FFFF) | ((r.y & 0x7FFF) << 17);
        int pos = atomicAdd(&cur[dl], 1);
        if (pos < S2_CAP) stage[pos] = r2;
        else              rec2[s0 + pos] = r2;
    }
    __syncthreads();
    for (int i = t; i < n && i < S2_CAP; i += BS2)
        rec2[s0 + i] = stage[i];
}

// ---------------------------------------------------------------------------
// Layer 0 fused (8 lanes/node, 4-deep batching): aggregate xpad,
// relu, emit p1 (fp16) + oinit1.
// ---------------------------------------------------------------------------
__global__ void layer0_kernel(const __half* __restrict__ xpad,
                              const uint32_t* __restrict__ rec,
                              const int2* __restrict__ rowcnt,
                              const float* __restrict__ wrel0, const float* __restrict__ brel0,
                              const float* __restrict__ wroot0,
                              const float* __restrict__ wrel1, const float* __restrict__ brel1,
                              const float* __restrict__ wroot1,
                              __half* __restrict__ pn, float* __restrict__ oinitn) {
    __shared__ float s_wrel0[6 * 20], s_wroot0[6 * 20], s_b0[20];
    __shared__ float s_wrel1[20 * 15], s_wroot1[20 * 15], s_b1[15];
    for (int t = threadIdx.x; t < 120; t += BLOCK) {
        s_wrel0[t]  = wrel0[t];
        s_wroot0[t] = wroot0[t];
    }
    for (int t = threadIdx.x; t < 300; t += BLOCK) {
        s_wrel1[t]  = wrel1[t];
        s_wroot1[t] = wroot1[t];
    }
    if (threadIdx.x < 20) s_b0[threadIdx.x] = brel0[threadIdx.x];
    if (threadIdx.x < 15) s_b1[threadIdx.x] = brel1[threadIdx.x];
    __syncthreads();

    int t = blockIdx.x * blockDim.x + threadIdx.x;
    int node = t >> 3;
    int q    = t & 7;

    float agg[6] = {0.f, 0.f, 0.f, 0.f, 0.f, 0.f};
    const int2 rc = rowcnt[node];
    const int s = rc.x;
    const int e = rc.x + rc.y;
    for (int k = s + q; k < e; k += 32) {
        uint32_t rv[4];
        float    wv[4];
        #pragma unroll
        for (int u = 0; u < 4; ++u) {
            int kk = k + 8 * u;
            int kc = kk < e ? kk : (e - 1);
            rv[u] = rec[kc];
            wv[u] = kk < e ? (float)(rv[u] >> 17) * W_INV : 0.f;
        }
        uint4 raw[4];
        #pragma unroll
        for (int u = 0; u < 4; ++u)
            raw[u] = *(const uint4*)(xpad + (size_t)(rv[u] & 0x1FFFF) * 8);
        #pragma unroll
        for (int u = 0; u < 4; ++u) {
            const __half2* h = (const __half2*)&raw[u];
            float w = wv[u];
            agg[0] += w * __low2float(h[0]);  agg[1] += w * __high2float(h[0]);
            agg[2] += w * __low2float(h[1]);  agg[3] += w * __high2float(h[1]);
            agg[4] += w * __low2float(h[2]);  agg[5] += w * __high2float(h[2]);
        }
    }
    #pragma unroll
    for (int i = 0; i < 6; ++i) {
        agg[i] += __shfl_xor(agg[i], 1);
        agg[i] += __shfl_xor(agg[i], 2);
        agg[i] += __shfl_xor(agg[i], 4);
    }
    uint4 raws = *(const uint4*)(xpad + (size_t)node * 8);
    const __half2* hs = (const __half2*)&raws;
    float xv[6] = { __low2float(hs[0]), __high2float(hs[0]),
                    __low2float(hs[1]), __high2float(hs[1]),
                    __low2float(hs[2]), __high2float(hs[2]) };
    float ov[20];
    #pragma unroll
    for (int j = 0; j < 20; ++j) {
        float o = s_b0[j];
        #pragma unroll
        for (int i = 0; i < 6; ++i)
            o += agg[i] * s_wrel0[i * 20 + j] + xv[i] * s_wroot0[i * 20 + j];
        ov[j] = fmaxf(o, 0.f);
    }
    {
        float pk[2] = {0.f, 0.f};
        #pragma unroll
        for (int kk = 0; kk < 2; ++kk) {
            int k = 2 * q + kk;
            if (k < 15) {
                float sacc = 0.f;
                #pragma unroll
                for (int j = 0; j < 20; ++j) sacc += ov[j] * s_wrel1[j * 15 + k];
                pk[kk] = sacc;
            }
        }
        ((__half2*)(pn + (size_t)node * 16))[q] =
            __halves2half2(__float2half(pk[0]), __float2half(pk[1]));
    }
    #pragma unroll
    for (int kk = 0; kk < 2; ++kk) {
        int k = q + kk * 8;
        if (k < 15) {
            float sacc = s_b1[k];
            #pragma unroll
            for (int j = 0; j < 20; ++j) sacc += ov[j] * s_wroot1[j * 15 + k];
            oinitn[(size_t)node * 15 + k] = sacc;
        }
    }
}

// ---------------------------------------------------------------------------
// Fused gather layer (8 lanes/node, 4-deep batching): aggregate
// p_i, relu + oinit_i, emit p_{i+1} + oinit_{i+1}. LAST: softmax.
// ---------------------------------------------------------------------------
template<int DOUT, int SPH, int NDOUT, int NSPH, bool LAST>
__global__ void gather_kernel(const __half* __restrict__ p, const float* __restrict__ oinit,
                              const uint32_t* __restrict__ rec,
                              const int2* __restrict__ rowcnt,
                              const float* __restrict__ wrel_n, const float* __restrict__ brel_n,
                              const float* __restrict__ wroot_n,
                              __half* __restrict__ pn, float* __restrict__ oinitn,
                              float* __restrict__ out) {
    __shared__ float s_wrel[LAST ? 1 : DOUT * NDOUT];
    __shared__ float s_wroot[LAST ? 1 : DOUT * NDOUT];
    __shared__ float s_b[LAST ? 1 : (NDOUT > 0 ? NDOUT : 1)];
    if constexpr (!LAST) {
        for (int t = threadIdx.x; t < DOUT * NDOUT; t += BLOCK) {
            s_wrel[t]  = wrel_n[t];
            s_wroot[t] = wroot_n[t];
        }
        if (threadIdx.x < NDOUT) s_b[threadIdx.x] = brel_n[threadIdx.x];
        __syncthreads();
    }

    int t = blockIdx.x * blockDim.x + threadIdx.x;
    int node = t >> 3;
    int q    = t & 7;

    float af[SPH];
    #pragma unroll
    for (int i = 0; i < SPH; ++i) af[i] = 0.f;

    const int2 rc = rowcnt[node];
    const int s = rc.x;
    const int e = rc.x + rc.y;
    constexpr int NR = (SPH >= 8) ? SPH / 8 : 1;
    for (int k = s + q; k < e; k += 32) {
        uint32_t rv[4];
        float    wv[4];
        #pragma unroll
        for (int u = 0; u < 4; ++u) {
            int kk = k + 8 * u;
            int kc = kk < e ? kk : (e - 1);
            rv[u] = rec[kc];
            wv[u] = kk < e ? (float)(rv[u] >> 17) * W_INV : 0.f;
        }
        if constexpr (SPH >= 8) {
            uint4 raw[4 * NR];
            #pragma unroll
            for (int u = 0; u < 4; ++u) {
                const uint4* ps = (const uint4*)(p + (size_t)(rv[u] & 0x1FFFF) * SPH);
                #pragma unroll
                for (int v = 0; v < NR; ++v) raw[u * NR + v] = ps[v];
            }
            #pragma unroll
            for (int u = 0; u < 4; ++u) {
                float w = wv[u];
                #pragma unroll
                for (int v = 0; v < NR; ++v) {
                    const __half2* h = (const __half2*)&raw[u * NR + v];
                    #pragma unroll
                    for (int jj = 0; jj < 4; ++jj) {
                        af[v * 8 + 2 * jj]     += w * __low2float(h[jj]);
                        af[v * 8 + 2 * jj + 1] += w * __high2float(h[jj]);
                    }
                }
            }
        } else {
            uint32_t raw[4];
            #pragma unroll
            for (int u = 0; u < 4; ++u)
                raw[u] = *(const uint32_t*)(p + (size_t)(rv[u] & 0x1FFFF) * SPH);
            #pragma unroll
            for (int u = 0; u < 4; ++u) {
                __half2 h = *(const __half2*)&raw[u];
                af[0] += wv[u] * __low2float(h);
                af[1] += wv[u] * __high2float(h);
            }
        }
    }
    #pragma unroll
    for (int i = 0; i < SPH; ++i) {
        af[i] += __shfl_xor(af[i], 1);
        af[i] += __shfl_xor(af[i], 2);
        af[i] += __shfl_xor(af[i], 4);
    }

    if constexpr (LAST) {
        if (q == 0) {
            float o0 = af[0] + oinit[(size_t)node * 2 + 0];
            float o1 = af[1] + oinit[(size_t)node * 2 + 1];
            float m = fmaxf(o0, o1);
            float e0 = __expf(o0 - m), e1 = __expf(o1 - m);
            float inv = 1.f / (e0 + e1);
            out[(size_t)node * 2 + 0] = e0 * inv;
            out[(size_t)node * 2 + 1] = e1 * inv;
        }
    } else {
        float ov[DOUT];
        #pragma unroll
        for (int j = 0; j < DOUT; ++j)
            ov[j] = fmaxf(af[j] + oinit[(size_t)node * DOUT + j], 0.f);

        if (q < NSPH / 2) {
            float pk[2] = {0.f, 0.f};
            #pragma unroll
            for (int kk = 0; kk < 2; ++kk) {
                int k = 2 * q + kk;
                if (k < NDOUT) {
                    float sacc = 0.f;
                    #pragma unroll
                    for (int j = 0; j < DOUT; ++j) sacc += ov[j] * s_wrel[j * NDOUT + k];
                    pk[kk] = sacc;
                }
            }
            ((__half2*)(pn + (size_t)node * NSPH))[q] =
                __halves2half2(__float2half(pk[0]), __float2half(pk[1]));
        }
        #pragma unroll
        for (int kk = 0; kk < 2; ++kk) {
            int k = q + kk * 8;
            if (k < NDOUT) {
                float sacc = s_b[k];
                #pragma unroll
                for (int j = 0; j < DOUT; ++j) sacc += ov[j] * s_wroot[j * NDOUT + k];
                oinitn[(size_t)node * NDOUT + k] = sacc;
            }
        }
    }
}

// ---------------------------------------------------------------------------

extern "C" void kernel_launch(void* const* d_in, const int* in_sizes, int n_in,
                              void* d_out, int out_size, void* d_ws, size_t ws_size,
                              hipStream_t stream) {
    const float* x  = (const float*)d_in[0];
    const int*   ei = (const int*)d_in[1];
    const float* ew = (const float*)d_in[2];
    const float* wrel[5]  = { (const float*)d_in[3], (const float*)d_in[6],
                              (const float*)d_in[9], (const float*)d_in[12],
                              (const float*)d_in[15] };
    const float* brel[5]  = { (const float*)d_in[4], (const float*)d_in[7],
                              (const float*)d_in[10], (const float*)d_in[13],
                              (const float*)d_in[16] };
    const float* wroot[5] = { (const float*)d_in[5], (const float*)d_in[8],
                              (const float*)d_in[11], (const float*)d_in[14],
                              (const float*)d_in[17] };

    char* ws = (char*)d_ws;
    size_t off = 0;
    auto alloc = [&](size_t bytes) -> void* {
        void* ptr = ws + off;
        off += (bytes + 255) & ~(size_t)255;
        return ptr;
    };
    // regionA: rec1 during sort (25.6 MB); p/oinit ping-pong during layers
    char*     regionA   = (char*)alloc((size_t)N_EDGES * 8);
    uint2*    rec1      = (uint2*)regionA;
    __half*   pA        = (__half*)regionA;                              // 3.2 MB
    __half*   pB        = (__half*)(regionA + (size_t)4  * 1024 * 1024); // 3.2 MB
    float*    oA        = (float*)(regionA + (size_t)8  * 1024 * 1024);  // 6 MB
    float*    oB        = (float*)(regionA + (size_t)16 * 1024 * 1024);  // 6 MB
    uint32_t* rec2      = (uint32_t*)alloc((size_t)N_EDGES * 4);         // 12.8 MB
    __half*   xpad      = (__half*)alloc((size_t)N_NODES * 8 * 2);       // 1.6 MB
    int*      hist_g    = (int*)alloc((size_t)NCH_H * NB * 4);           // 3.2 MB
    int*      off_g     = (int*)alloc((size_t)NCH_H * NB * 4);           // 3.2 MB
    int*      tot       = (int*)alloc((size_t)NB * 4);
    int*      bstart    = (int*)alloc((size_t)NB * 4);
    int2*     rowcnt    = (int2*)alloc((size_t)N_NODES * 8);

    const int* srcv = ei;            // edge_index row 0
    const int* dstv = ei + N_EDGES;  // edge_index row 1

    const int gN8 = (8 * N_NODES + BLOCK - 1) / BLOCK;      // 3125

    hist_kernel     <<<NCH_H, BLOCK, 0, stream>>>(dstv, hist_g, x, xpad);
    chunkscan_kernel<<<(NB + 3) / 4, BLOCK, 0, stream>>>(hist_g, off_g, tot);
    scan_kernel     <<<1, SCAN_T, 0, stream>>>(tot, bstart);
    scatter1_kernel <<<NCH_S, BS1, 0, stream>>>(srcv, dstv, ew, bstart, off_g, hist_g, rec1);
    scatter2_kernel <<<NB, BS2, 0, stream>>>(rec1, bstart, tot, rec2, rowcnt);

    // L0 fused: 6 -> 20 (relu) -> emit p1 [15, SPH 16] + oinit1
    layer0_kernel<<<gN8, BLOCK, 0, stream>>>(xpad, rec2, rowcnt,
                                             wrel[0], brel[0], wroot[0],
                                             wrel[1], brel[1], wroot[1], pA, oA);
    // g1: agg p1, out1 [15] -> p2 [10, SPH 16] + oinit2
    gather_kernel<15, 16, 10, 16, false><<<gN8, BLOCK, 0, stream>>>(
        pA, oA, rec2, rowcnt, wrel[2], brel[2], wroot[2], pB, oB, nullptr);
    // g2: agg p2, out2 [10] -> p3 [5, SPH 8] + oinit3
    gather_kernel<10, 16, 5, 8, false><<<gN8, BLOCK, 0, stream>>>(
        pB, oB, rec2, rowcnt, wrel[3], brel[3], wroot[3], pA, oA, nullptr);
    // g3: agg p3, out3 [5] -> p4 [2, SPH 2] + oinit4
    gather_kernel<5, 8, 2, 2, false><<<gN8, BLOCK, 0, stream>>>(
        pA, oA, rec2, rowcnt, wrel[4], brel[4], wroot[4], pB, oB, nullptr);
    // g4: agg p4, softmax -> d_out
    gather_kernel<2, 2, 0, 0, true><<<gN8, BLOCK, 0, stream>>>(
        pB, oB, rec2, rowcnt, nullptr, nullptr, nullptr,
        nullptr, nullptr, (float*)d_out);
}